// Round 1
// baseline (399.825 us; speedup 1.0000x reference)
//
#include <hip/hip_runtime.h>

#define HS   1024
#define SEQ  512
#define NBAT 64
#define INSZ 8
#define NM   4
#define DD   12

// DPP-based add: v += dpp_move(v). old=0 so masked/invalid lanes add 0.
#define DPP_ADD(v, ctrl, rmask, bmask) \
  v += __int_as_float(__builtin_amdgcn_update_dpp(0, __float_as_int(v), ctrl, rmask, bmask, true))

// Canonical gfx9 wave64 sum (LLVM AtomicOptimizer sequence). Lane 63 holds the
// full 64-lane total afterwards. Two values interleaved to pipeline latency.
__device__ __forceinline__ void wave64_sum2(float &a, float &b){
  DPP_ADD(a, 0x111, 0xf, 0xf); DPP_ADD(b, 0x111, 0xf, 0xf);  // row_shr:1
  DPP_ADD(a, 0x112, 0xf, 0xf); DPP_ADD(b, 0x112, 0xf, 0xf);  // row_shr:2
  DPP_ADD(a, 0x114, 0xf, 0xe); DPP_ADD(b, 0x114, 0xf, 0xe);  // row_shr:4
  DPP_ADD(a, 0x118, 0xf, 0xc); DPP_ADD(b, 0x118, 0xf, 0xc);  // row_shr:8
  DPP_ADD(a, 0x142, 0xa, 0xf); DPP_ADD(b, 0x142, 0xa, 0xf);  // row_bcast:15
  DPP_ADD(a, 0x143, 0xc, 0xf); DPP_ADD(b, 0x143, 0xc, 0xf);  // row_bcast:31
}

__device__ __forceinline__ float fast_tanh(float x){
  // 1 - 2*rcp(e^{2x}+1): v_exp + v_rcp only. Saturates exactly at +/-inf.
  float e = __expf(x + x);
  float r = __builtin_amdgcn_rcpf(e + 1.0f);
  return __builtin_fmaf(-2.0f, r, 1.0f);
}

// Fast-math-proof NaN test (bit pattern, not FP compare).
__device__ __forceinline__ unsigned is_nan_bits(float x){
  return (__float_as_uint(x) & 0x7fffffffu) > 0x7f800000u ? 1u : 0u;
}

__global__ __launch_bounds__(256,1)
void rnn_scan(const float* __restrict__ x,
              const float* __restrict__ eps,
              const float* __restrict__ means,
              const float* __restrict__ tril,
              const float* __restrict__ mw,
              float* __restrict__ out)
{
  const int b    = blockIdx.x;
  const int tid  = threadIdx.x;
  const int wave = tid >> 6;
  const int lane = tid & 63;

  __shared__ float  xs[SEQ*INSZ];                 // 16 KB: whole input sequence
  __shared__ float2 ring[SEQ][4];                 // 16 KB: write-once wave partials,
                                                  // NaN-init. Data IS the ready flag:
                                                  // no __syncthreads in the scan loop.
  __shared__ __align__(16) float outb[SEQ*10];    // 20 KB: staged outputs

  // ---- mixture weights ----
  float w[NM];
  {
    float s = 0.f;
    #pragma unroll
    for (int k=0;k<NM;k++){ w[k] = fmaxf(mw[k], 1e-6f); s += w[k]; }
    float inv = 1.0f/s;
    #pragma unroll
    for (int k=0;k<NM;k++) w[k] *= inv;
  }

  // ---- preprocessing: mixed[i, 0:12] for owned rows i = tid + j*256 ----
  float m0[4],m1[4],n0[4],n1[4],h[4];
  float2 Im2[4][4];
  #pragma unroll
  for (int j=0;j<4;j++){
    const int i = tid + j*256;
    float ep[NM][DD];
    #pragma unroll
    for (int k=0;k<NM;k++)
      #pragma unroll
      for (int d=0;d<DD;d++)
        ep[k][d] = eps[(k*HS + i)*DD + d];
    float mix[DD];
    #pragma unroll
    for (int e=0;e<DD;e++){
      float a = 0.f;
      #pragma unroll
      for (int k=0;k<NM;k++){
        float se = means[k*DD+e];
        for (int d=0; d<e; d++)                       // strict lower triangle
          se += ep[k][d]*tril[(k*DD+e)*DD + d];
        float dg = fabsf(tril[(k*DD+e)*DD + e] - 1e-12f) + 1e-12f;  // diagonal
        se += ep[k][e]*dg;
        a += w[k]*se;
      }
      mix[e] = a;
    }
    m0[j]=mix[0]; m1[j]=mix[1]; n0[j]=mix[2]; n1[j]=mix[3];
    #pragma unroll
    for (int e=0;e<4;e++) Im2[j][e]=make_float2(mix[4+2*e], mix[5+2*e]);
    h[j]=0.f;
  }

  // NaN-fill the ring (each slot written exactly once later) + stage x[b]
  for (int idx=tid; idx<SEQ*4; idx+=256)
    ((uint2*)ring)[idx] = make_uint2(0x7fc00000u, 0x7fc00000u);
  for (int idx=tid; idx<SEQ*INSZ; idx+=256) xs[idx] = x[b*SEQ*INSZ + idx];
  __syncthreads();   // covers ring init + xs staging; last barrier before the scan

  const float alpha = 0.1f;
  const float oma   = 0.9f;
  const float scl   = 500.0f/1024.0f;
  const float as    = alpha*scl;
  float o = 0.f;
  const float2* xs2 = (const float2*)xs;

  #pragma unroll 2
  for (int t=0;t<SEQ;t++){
    // u_r = sum_i tanh(h_i)*n[i,r] -- the only global coupling per step
    float u0=0.f, u1=0.f;
    #pragma unroll
    for (int j=0;j<4;j++){
      float th = fast_tanh(h[j]);
      u0 = __builtin_fmaf(th, n0[j], u0);
      u1 = __builtin_fmaf(th, n1[j], u1);
    }
    wave64_sum2(u0, u1);                 // DPP butterfly, lane 63 has totals
    if (lane==63) ring[t][wave] = make_float2(u0,u1);   // write-once publish

    // inj = x_t @ I^T for owned rows -- independent of u, covers handoff latency
    float inj[4];
    #pragma unroll
    for (int j=0;j<4;j++){
      float2 acc = make_float2(0.f,0.f);
      #pragma unroll
      for (int e=0;e<4;e++){
        float2 xe = xs2[t*4+e];
        acc.x = __builtin_fmaf(xe.x, Im2[j][e].x, acc.x);
        acc.y = __builtin_fmaf(xe.y, Im2[j][e].y, acc.y);
      }
      inj[j] = acc.x + acc.y;
    }

    // Barrier-free combine: poll the 4 write-once slots. Sum order identical to
    // the old barrier version; NaN in any unwritten word propagates into U and
    // triggers retry. Real partials are tanh-bounded -> never NaN.
    float U0, U1;
    {
      volatile const float* vp = (volatile const float*)(&ring[t][0]);
      for (;;){
        float a0=vp[0], a1=vp[1], a2=vp[2], a3=vp[3];
        float a4=vp[4], a5=vp[5], a6=vp[6], a7=vp[7];
        U0 = (a0+a2)+(a4+a6);
        U1 = (a1+a3)+(a5+a7);
        if (!(is_nan_bits(U0) | is_nan_bits(U1))) break;
      }
    }

    #pragma unroll
    for (int j=0;j<4;j++){
      float mu = __builtin_fmaf(m1[j], U1, m0[j]*U0);
      h[j] = __builtin_fmaf(oma, h[j],
             __builtin_fmaf(as, mu, alpha*inj[j]));
    }

    // o_t = pinv(span) @ h_t exactly (h lives in col(span), pinv@span = I_10)
    if (tid < 10){
      float add = (tid==0) ? scl*U0 : (tid==1) ? scl*U1 : xs[t*8 + tid-2];
      o = __builtin_fmaf(oma, o, alpha*add);
      outb[t*10+tid] = o;
    }
  }

  __syncthreads();
  // burst-dump staged outputs, coalesced float4
  const float4* ob4 = (const float4*)outb;
  float4* o4 = (float4*)out + b*(SEQ*10/4);
  for (int idx=tid; idx<SEQ*10/4; idx+=256) o4[idx] = ob4[idx];
}

extern "C" void kernel_launch(void* const* d_in, const int* in_sizes, int n_in,
                              void* d_out, int out_size, void* d_ws, size_t ws_size,
                              hipStream_t stream) {
  const float* x     = (const float*)d_in[0];  // (64,512,8)
  const float* eps   = (const float*)d_in[1];  // (4,1024,12)
  const float* means = (const float*)d_in[2];  // (4,12)
  const float* tril  = (const float*)d_in[3];  // (4,12,12)
  const float* mw    = (const float*)d_in[4];  // (4,)
  float* out = (float*)d_out;                  // (64,512,10) fp32

  rnn_scan<<<NBAT, 256, 0, stream>>>(x, eps, means, tril, mw, out);
}

// Round 2
// 381.033 us; speedup vs baseline: 1.0493x; 1.0493x over previous
//
#include <hip/hip_runtime.h>

#define HS   1024
#define SEQ  512
#define NBAT 64
#define INSZ 8
#define NM   4
#define DD   12

#define ALPHA 0.1f
#define OMA   0.9f
#define SCL   (500.0f/1024.0f)
#define AS    (ALPHA*SCL)

// exp(2h) evaluated as exp2(GS*h) when native exp2 builtin exists, else expf(2h).
// All scaled states (A, B, C/Yg) carry the SAME GS factor, fixed at compile time.
#if __has_builtin(__builtin_amdgcn_exp2f)
  #define GS 2.8853900817779268f      /* 2*log2(e) */
  #define EXPG(v) __builtin_amdgcn_exp2f(v)
#else
  #define GS 2.0f
  #define EXPG(v) __expf(v)
#endif

typedef float f2 __attribute__((ext_vector_type(2)));
__device__ __forceinline__ f2 mk2(float a, float b){ f2 r; r.x=a; r.y=b; return r; }
__device__ __forceinline__ f2 splat2(float a){ return mk2(a,a); }
__device__ __forceinline__ f2 fma2(f2 a, f2 b, f2 c){
  f2 r; r.x=fmaf(a.x,b.x,c.x); r.y=fmaf(a.y,b.y,c.y); return r;
}

// DPP-based add: v += dpp_move(v). old=0 so masked/invalid lanes add 0.
#define DPP_ADD(v, ctrl, rmask, bmask) \
  v += __int_as_float(__builtin_amdgcn_update_dpp(0, __float_as_int(v), ctrl, rmask, bmask, true))

// Canonical gfx9 wave64 sum. Lane 63 holds the full 64-lane total afterwards.
__device__ __forceinline__ void wave64_sum2(float &a, float &b){
  DPP_ADD(a, 0x111, 0xf, 0xf); DPP_ADD(b, 0x111, 0xf, 0xf);  // row_shr:1
  DPP_ADD(a, 0x112, 0xf, 0xf); DPP_ADD(b, 0x112, 0xf, 0xf);  // row_shr:2
  DPP_ADD(a, 0x114, 0xf, 0xe); DPP_ADD(b, 0x114, 0xf, 0xe);  // row_shr:4
  DPP_ADD(a, 0x118, 0xf, 0xc); DPP_ADD(b, 0x118, 0xf, 0xc);  // row_shr:8
  DPP_ADD(a, 0x142, 0xa, 0xf); DPP_ADD(b, 0x142, 0xa, 0xf);  // row_bcast:15
  DPP_ADD(a, 0x143, 0xc, 0xf); DPP_ADD(b, 0x143, 0xc, 0xf);  // row_bcast:31
}
#define RD63(v) __int_as_float(__builtin_amdgcn_readlane(__float_as_int(v), 63))

// mixed[e] for unit i, e in [E0,E1)
template<int E0, int E1>
__device__ __forceinline__ void mix_unit(int i, const float* __restrict__ eps,
                                         const float* __restrict__ means,
                                         const float* __restrict__ tril,
                                         const float* w, float* outm){
  float ep[NM][DD];
  #pragma unroll
  for (int k=0;k<NM;k++){
    const float4* p = (const float4*)(eps + (size_t)(k*HS + i)*DD);
    float4 r0=p[0], r1=p[1], r2=p[2];
    ep[k][0]=r0.x; ep[k][1]=r0.y; ep[k][2]=r0.z; ep[k][3]=r0.w;
    ep[k][4]=r1.x; ep[k][5]=r1.y; ep[k][6]=r1.z; ep[k][7]=r1.w;
    ep[k][8]=r2.x; ep[k][9]=r2.y; ep[k][10]=r2.z; ep[k][11]=r2.w;
  }
  #pragma unroll
  for (int e=E0;e<E1;e++){
    float a = 0.f;
    #pragma unroll
    for (int k=0;k<NM;k++){
      float se = means[k*DD+e];
      #pragma unroll
      for (int d=0; d<e; d++) se = fmaf(ep[k][d], tril[(k*DD+e)*DD+d], se);
      float dg = fabsf(tril[(k*DD+e)*DD+e] - 1e-12f) + 1e-12f;
      se = fmaf(ep[k][e], dg, se);
      a = fmaf(w[k], se, a);
    }
    outm[e-E0] = a;
  }
}

// ---------------- Kernel 1: C[b][t][i] = I_i . Yg_b(t)  (GS-scaled) -----------
__global__ __launch_bounds__(256,1)
void gemm_c(const float* __restrict__ x, const float* __restrict__ eps,
            const float* __restrict__ means, const float* __restrict__ tril,
            const float* __restrict__ mw, float* __restrict__ C)
{
  const int b = blockIdx.x >> 2, q = blockIdx.x & 3;
  const int tid = threadIdx.x;
  __shared__ float xs[SEQ*INSZ];   // 16 KB
  __shared__ float yb[128][8];     // 4 KB window of Yg

  float w[NM];
  { float s=0.f;
    #pragma unroll
    for (int k=0;k<NM;k++){ w[k]=fmaxf(mw[k],1e-6f); s+=w[k]; }
    float inv=1.0f/s;
    #pragma unroll
    for (int k=0;k<NM;k++) w[k]*=inv; }

  float I[4][8];
  #pragma unroll
  for (int j=0;j<4;j++) mix_unit<4,12>(tid*4+j, eps, means, tril, w, I[j]);

  { const float4* xp=(const float4*)(x + (size_t)b*SEQ*INSZ);
    float4* xd=(float4*)xs;
    for (int idx=tid; idx<SEQ*INSZ/4; idx+=256) xd[idx]=xp[idx]; }
  __syncthreads();

  if (tid < 8){
    float Y=0.f; const int t0=q*128, tend=t0+128;
    for (int t=0;t<tend;t++){
      if (t>=t0) yb[t-t0][tid]=Y;                 // Yg consumed at step t
      Y = fmaf(OMA, Y, (GS*ALPHA)*xs[t*8+tid]);   // then fold x_t in
    }
  }
  __syncthreads();

  float* Cb = C + ((size_t)b*SEQ + (size_t)q*128)*HS + tid*4;
  for (int tt=0; tt<128; tt++){
    float4 ya=((float4*)yb[tt])[0], yc=((float4*)yb[tt])[1];
    float cv[4];
    #pragma unroll
    for (int j=0;j<4;j++){
      float a =       I[j][0]*ya.x;
      a = fmaf(I[j][1],ya.y,a); a = fmaf(I[j][2],ya.z,a); a = fmaf(I[j][3],ya.w,a);
      a = fmaf(I[j][4],yc.x,a); a = fmaf(I[j][5],yc.y,a);
      a = fmaf(I[j][6],yc.z,a); a = fmaf(I[j][7],yc.w,a);
      cv[j]=a;
    }
    *(float4*)(Cb + (size_t)tt*HS) = make_float4(cv[0],cv[1],cv[2],cv[3]);
  }
}

// ---------------- Kernel 2: single-wave-per-batch serial scan -----------------
template<int PRE>
__global__ __launch_bounds__(64,1)
void rnn_scan(const float* __restrict__ x, const float* __restrict__ eps,
              const float* __restrict__ means, const float* __restrict__ tril,
              const float* __restrict__ mw, float* __restrict__ out,
              const float* __restrict__ C)
{
  const int b = blockIdx.x;
  const int lane = threadIdx.x;           // 64 threads = 1 wave, 16 units/lane

  __shared__ float xs[SEQ*INSZ];                // 16 KB
  __shared__ __align__(16) float outb[SEQ*10];  // 20 KB

  float w[NM];
  { float s=0.f;
    #pragma unroll
    for (int k=0;k<NM;k++){ w[k]=fmaxf(mw[k],1e-6f); s+=w[k]; }
    float inv=1.0f/s;
    #pragma unroll
    for (int k=0;k<NM;k++) w[k]*=inv; }

  // params for unit pairs p: units 16*lane+2p, 16*lane+2p+1
  f2 m0v[8], m1v[8], n0v[8], n1v[8];
  float sn0=0.f, sn1=0.f;
  #pragma unroll
  for (int p=0;p<8;p++){
    float mA[4], mB[4];
    mix_unit<0,4>(16*lane+2*p,   eps, means, tril, w, mA);
    mix_unit<0,4>(16*lane+2*p+1, eps, means, tril, w, mB);
    m0v[p]=mk2(mA[0],mB[0]); m1v[p]=mk2(mA[1],mB[1]);
    sn0 += mA[2]+mB[2];      sn1 += mA[3]+mB[3];
    n0v[p]=mk2(-2.f*mA[2], -2.f*mB[2]);
    n1v[p]=mk2(-2.f*mA[3], -2.f*mB[3]);
  }
  wave64_sum2(sn0, sn1);
  const float N0 = RD63(sn0), N1 = RD63(sn1);

  // fallback-only state (DCE'd when PRE)
  f2 Iv[8][8]; float Yg[8];
  const float AG = GS*ALPHA;
  if constexpr(!PRE){
    #pragma unroll
    for (int p=0;p<8;p++){
      float IA[8], IB[8];
      mix_unit<4,12>(16*lane+2*p,   eps, means, tril, w, IA);
      mix_unit<4,12>(16*lane+2*p+1, eps, means, tril, w, IB);
      #pragma unroll
      for (int e=0;e<8;e++) Iv[p][e]=mk2(IA[e],IB[e]);
    }
    #pragma unroll
    for (int e=0;e<8;e++) Yg[e]=0.f;
  }

  { const float4* xp=(const float4*)(x + (size_t)b*SEQ*INSZ);
    float4* xd=(float4*)xs;
    for (int idx=lane; idx<SEQ*INSZ/4; idx+=64) xd[idx]=xp[idx]; }
  __syncthreads();

  const float CA = GS*AS;
  float A=0.f, Bst=0.f, o=0.f;

  const float4* Cp = PRE ? ((const float4*)C + (size_t)b*SEQ*(HS/4) + lane*4)
                         : (const float4*)nullptr;
  #define CLOAD(v0,v1,v2,v3,T) { const float4* p_ = Cp + (size_t)(T)*(HS/4); \
    v0=p_[0]; v1=p_[1]; v2=p_[2]; v3=p_[3]; }

  float4 c00{},c01{},c02{},c03{}, c10{},c11{},c12{},c13{},
         c20{},c21{},c22{},c23{}, c30{},c31{},c32{},c33{};
  if constexpr(PRE){
    CLOAD(c00,c01,c02,c03,0) CLOAD(c10,c11,c12,c13,1)
    CLOAD(c20,c21,c22,c23,2) CLOAD(c30,c31,c32,c33,3)
  }

  #define STEP(T, TN, v0,v1,v2,v3) { \
    f2 g[8]; \
    if constexpr(PRE){ \
      g[0]=mk2(v0.x,v0.y); g[1]=mk2(v0.z,v0.w); \
      g[2]=mk2(v1.x,v1.y); g[3]=mk2(v1.z,v1.w); \
      g[4]=mk2(v2.x,v2.y); g[5]=mk2(v2.z,v2.w); \
      g[6]=mk2(v3.x,v3.y); g[7]=mk2(v3.z,v3.w); \
    } else { \
      _Pragma("unroll") for (int p=0;p<8;p++){ \
        f2 a = mk2(0.f,0.f); \
        _Pragma("unroll") for (int e=0;e<8;e++) a = fma2(Iv[p][e], splat2(Yg[e]), a); \
        g[p]=a; } \
    } \
    { f2 A2=splat2(A), B2=splat2(Bst); \
      _Pragma("unroll") for (int p=0;p<8;p++){ \
        g[p]=fma2(m0v[p],A2,g[p]); g[p]=fma2(m1v[p],B2,g[p]); } } \
    if constexpr(PRE){ CLOAD(v0,v1,v2,v3,TN) } \
    else { float4 xa=((const float4*)xs)[(T)*2], xb=((const float4*)xs)[(T)*2+1]; \
      Yg[0]=fmaf(OMA,Yg[0],AG*xa.x); Yg[1]=fmaf(OMA,Yg[1],AG*xa.y); \
      Yg[2]=fmaf(OMA,Yg[2],AG*xa.z); Yg[3]=fmaf(OMA,Yg[3],AG*xa.w); \
      Yg[4]=fmaf(OMA,Yg[4],AG*xb.x); Yg[5]=fmaf(OMA,Yg[5],AG*xb.y); \
      Yg[6]=fmaf(OMA,Yg[6],AG*xb.z); Yg[7]=fmaf(OMA,Yg[7],AG*xb.w); } \
    f2 ua=mk2(0.f,0.f), ub=mk2(0.f,0.f); \
    _Pragma("unroll") for (int p=0;p<8;p++){ \
      f2 ex = mk2(EXPG(g[p].x), EXPG(g[p].y)); \
      f2 dd = mk2(ex.x+1.f, ex.y+1.f); \
      f2 rr = mk2(__builtin_amdgcn_rcpf(dd.x), __builtin_amdgcn_rcpf(dd.y)); \
      ua = fma2(rr, n0v[p], ua); ub = fma2(rr, n1v[p], ub); } \
    float u0=ua.x+ua.y, u1=ub.x+ub.y; \
    wave64_sum2(u0,u1); \
    float U0 = N0 + RD63(u0); \
    float U1 = N1 + RD63(u1); \
    A   = fmaf(CA,U0, 0.9f*A); \
    Bst = fmaf(CA,U1, 0.9f*Bst); \
    if (lane<10){ \
      float add = lane==0 ? SCL*U0 : lane==1 ? SCL*U1 : xs[(T)*8+lane-2]; \
      o = fmaf(OMA, o, ALPHA*add); outb[(T)*10+lane]=o; } \
  }

  #pragma unroll 1
  for (int t=0; t<SEQ; t+=4){
    STEP(t,   (t+4)&(SEQ-1), c00,c01,c02,c03)
    STEP(t+1, (t+5)&(SEQ-1), c10,c11,c12,c13)
    STEP(t+2, (t+6)&(SEQ-1), c20,c21,c22,c23)
    STEP(t+3, (t+7)&(SEQ-1), c30,c31,c32,c33)
  }
  #undef STEP
  #undef CLOAD

  __syncthreads();
  const float4* ob4 = (const float4*)outb;
  float4* o4 = (float4*)out + (size_t)b*(SEQ*10/4);
  for (int idx=lane; idx<SEQ*10/4; idx+=64) o4[idx]=ob4[idx];
}

extern "C" void kernel_launch(void* const* d_in, const int* in_sizes, int n_in,
                              void* d_out, int out_size, void* d_ws, size_t ws_size,
                              hipStream_t stream) {
  const float* x     = (const float*)d_in[0];  // (64,512,8)
  const float* eps   = (const float*)d_in[1];  // (4,1024,12)
  const float* means = (const float*)d_in[2];  // (4,12)
  const float* tril  = (const float*)d_in[3];  // (4,12,12)
  const float* mw    = (const float*)d_in[4];  // (4,)
  float* out = (float*)d_out;                  // (64,512,10) fp32

  const size_t cbytes = (size_t)NBAT*SEQ*HS*sizeof(float);   // 128 MB
  if (d_ws && ws_size >= cbytes){
    gemm_c<<<NBAT*4, 256, 0, stream>>>(x, eps, means, tril, mw, (float*)d_ws);
    rnn_scan<1><<<NBAT, 64, 0, stream>>>(x, eps, means, tril, mw, out, (const float*)d_ws);
  } else {
    rnn_scan<0><<<NBAT, 64, 0, stream>>>(x, eps, means, tril, mw, out, nullptr);
  }
}